// Round 1
// baseline (339.069 us; speedup 1.0000x reference)
//
#include <hip/hip_runtime.h>

#define NPTS 500000
#define RPLANE 128
#define FDIM 32
#define PLSZ (RPLANE * RPLANE * FDIM)
#define TM 64

typedef __bf16 bfx8 __attribute__((ext_vector_type(8)));
typedef float f32x4 __attribute__((ext_vector_type(4)));

__device__ __forceinline__ unsigned short f2bf(float f) {
    unsigned int u = __builtin_bit_cast(unsigned int, f);
    unsigned int r = (u + 0x7FFFu + ((u >> 16) & 1u)) >> 16;
    return (unsigned short)r;
}

__device__ __forceinline__ bfx8 ld_frag_g(const unsigned short* p) {
    uint4 raw = *(const uint4*)p;
    return __builtin_bit_cast(bfx8, raw);
}

// Bilinear sample of 4 consecutive features at (u -> x axis, v -> y axis).
__device__ __forceinline__ float4 interp4(const float* __restrict__ plane, float u, float v, int f0) {
    float x = fminf(fmaxf(u, 0.f), 1.f) * 127.0f;
    float y = fminf(fmaxf(v, 0.f), 1.f) * 127.0f;
    float xf = fminf(fmaxf(floorf(x), 0.f), 126.f);
    float yf = fminf(fmaxf(floorf(y), 0.f), 126.f);
    int x0 = (int)xf, y0 = (int)yf;
    float fx = x - xf, fy = y - yf;
    const float* p = plane + (size_t)(y0 * RPLANE + x0) * FDIM + f0;
    float4 a00 = *(const float4*)p;
    float4 a01 = *(const float4*)(p + FDIM);
    float4 a10 = *(const float4*)(p + RPLANE * FDIM);
    float4 a11 = *(const float4*)(p + RPLANE * FDIM + FDIM);
    float w00 = (1.f - fx) * (1.f - fy);
    float w01 = fx * (1.f - fy);
    float w10 = (1.f - fx) * fy;
    float w11 = fx * fy;
    float4 r;
    r.x = a00.x * w00 + a01.x * w01 + a10.x * w10 + a11.x * w11;
    r.y = a00.y * w00 + a01.y * w01 + a10.y * w10 + a11.y * w11;
    r.z = a00.z * w00 + a01.z * w01 + a10.z * w10 + a11.z * w11;
    r.w = a00.w * w00 + a01.w * w01 + a10.w * w10 + a11.w * w11;
    return r;
}

// Repack a row-major f32 weight matrix [K][Ncols] into bf16 MFMA-B-fragment order:
// block b = ct*(K/32)+ks holds lane l elems j: B[ks*32+(l>>4)*8+j][ct*16+(l&15)].
__global__ void prep_w(const float* __restrict__ W, unsigned short* __restrict__ dst,
                       int K, int Ncols, int total) {
    int idx = blockIdx.x * blockDim.x + threadIdx.x;
    if (idx >= total) return;
    int j = idx & 7;
    int l = (idx >> 3) & 63;
    int b = idx >> 9;
    int KS = K >> 5;
    int ct = b / KS;
    int ks = b - ct * KS;
    int k = ks * 32 + ((l >> 4) << 3) + j;
    int col = ct * 16 + (l & 15);
    dst[idx] = f2bf(W[(size_t)k * Ncols + col]);
}

// Passthrough outputs: out[0:3N)=rays, out[3N:7N)=rot, out[7N:8N)=h_emb[:,0]
__global__ void pass_copy(const float* __restrict__ rays, const float* __restrict__ rot,
                          const float* __restrict__ h, float* __restrict__ out) {
    const int total = NPTS * 8;
    for (int i = blockIdx.x * blockDim.x + threadIdx.x; i < total; i += gridDim.x * blockDim.x) {
        float v;
        if (i < NPTS * 3) v = rays[i];
        else if (i < NPTS * 7) v = rot[i - NPTS * 3];
        else v = h[(i - NPTS * 7) * 2];
        out[i] = v;
    }
}

__global__ __launch_bounds__(256) void fused_kernel(
    const float* __restrict__ rays, const float* __restrict__ time_emb,
    const float* __restrict__ shs_emb,
    const float* __restrict__ sp, const float* __restrict__ tp,
    const unsigned short* __restrict__ wf,
    const float* __restrict__ b_enc, const float* __restrict__ b1v,
    const float* __restrict__ b2v,
    float* __restrict__ out) {
    __shared__ unsigned short g_lds[TM][40];    // [point][feature], +8 pad
    __shared__ unsigned short f1[TM][264];      // [point][256], +8 pad
    __shared__ unsigned short f2s[TM][264];
    const int tid = threadIdx.x;
    const int base = blockIdx.x * TM;

    // ---- phase 0: plane-interp features, 8 lanes per point (4 features each) ----
    for (int rr = 0; rr < 2; ++rr) {
        int task = (rr << 8) + tid;
        int pl = task >> 3;
        int fg = task & 7;
        int p = base + pl;
        float4 g = make_float4(0.f, 0.f, 0.f, 0.f);
        if (p < NPTS) {
            float px = rays[p * 3 + 0], py = rays[p * 3 + 1], pz = rays[p * 3 + 2];
            const float inv = 1.0f / 1.6f;
            float xn = fminf(fmaxf(px * inv, -1.f), 1.f) * 0.5f + 0.5f;
            float yn = fminf(fmaxf(py * inv, -1.f), 1.f) * 0.5f + 0.5f;
            float zn = fminf(fmaxf(pz * inv, -1.f), 1.f) * 0.5f + 0.5f;
            float t = fminf(fmaxf(time_emb[p], 0.f), 1.f);
            int f0 = fg << 2;
            float4 s0 = interp4(sp, xn, yn, f0);
            float4 s1 = interp4(sp + PLSZ, xn, zn, f0);
            float4 s2 = interp4(sp + 2 * PLSZ, yn, zn, f0);
            float4 t0 = interp4(tp, xn, t, f0);
            float4 t1 = interp4(tp + PLSZ, yn, t, f0);
            float4 t2 = interp4(tp + 2 * PLSZ, zn, t, f0);
            g.x = s0.x * s1.x * s2.x * t0.x * t1.x * t2.x;
            g.y = s0.y * s1.y * s2.y * t0.y * t1.y * t2.y;
            g.z = s0.z * s1.z * s2.z * t0.z * t1.z * t2.z;
            g.w = s0.w * s1.w * s2.w * t0.w * t1.w * t2.w;
        }
        ushort4 gb;
        gb.x = f2bf(g.x); gb.y = f2bf(g.y); gb.z = f2bf(g.z); gb.w = f2bf(g.w);
        *(ushort4*)&g_lds[pl][fg << 2] = gb;
    }
    __syncthreads();

    const int wid = tid >> 6;
    const int lane = tid & 63;
    const int lrow = lane & 15;          // A row / B,D col within tile
    const int lk8 = (lane >> 4) << 3;    // k-chunk base
    const int drow = (lane >> 4) << 2;   // D row base

    // ---- layer 1: [64,32] @ [32,256] + b_enc, relu -> f1 ----
    bfx8 a1[4];
#pragma unroll
    for (int mt = 0; mt < 4; ++mt)
        a1[mt] = __builtin_bit_cast(bfx8, *(const uint4*)&g_lds[mt * 16 + lrow][lk8]);
#pragma unroll
    for (int ct = 0; ct < 4; ++ct) {
        int ctg = wid * 4 + ct;
        bfx8 b = ld_frag_g(wf + (size_t)ctg * 512 + lane * 8);
        float bias = b_enc[ctg * 16 + lrow];
#pragma unroll
        for (int mt = 0; mt < 4; ++mt) {
            f32x4 z = {0.f, 0.f, 0.f, 0.f};
            f32x4 acc = __builtin_amdgcn_mfma_f32_16x16x32_bf16(a1[mt], b, z, 0, 0, 0);
#pragma unroll
            for (int r2 = 0; r2 < 4; ++r2) {
                int row = mt * 16 + drow + r2;
                float v = fmaxf(acc[r2] + bias, 0.f);
                f1[row][ctg * 16 + lrow] = f2bf(v);
            }
        }
    }
    __syncthreads();

    // ---- layer 2: [64,256] @ [256,256] + b1, relu -> f2s ----
    const unsigned short* w1f = wf + 8192;
#pragma unroll
    for (int mt = 0; mt < 4; ++mt) {
        bfx8 A[8];
#pragma unroll
        for (int ks = 0; ks < 8; ++ks)
            A[ks] = __builtin_bit_cast(bfx8, *(const uint4*)&f1[mt * 16 + lrow][ks * 32 + lk8]);
#pragma unroll
        for (int ct = 0; ct < 4; ++ct) {
            int ctg = wid * 4 + ct;
            f32x4 acc = {0.f, 0.f, 0.f, 0.f};
#pragma unroll
            for (int ks = 0; ks < 8; ++ks) {
                bfx8 B = ld_frag_g(w1f + (size_t)(ctg * 8 + ks) * 512 + lane * 8);
                acc = __builtin_amdgcn_mfma_f32_16x16x32_bf16(A[ks], B, acc, 0, 0, 0);
            }
            float bias = b1v[ctg * 16 + lrow];
#pragma unroll
            for (int r2 = 0; r2 < 4; ++r2) {
                int row = mt * 16 + drow + r2;
                float v = fmaxf(acc[r2] + bias, 0.f);
                f2s[row][ctg * 16 + lrow] = f2bf(v);
            }
        }
    }
    __syncthreads();

    // ---- layer 3: [64,256] @ [256,48] + b2 + shs_emb -> out ----
    const unsigned short* w2f = wf + 73728;
    {
        int mt = wid;
        bfx8 A[8];
#pragma unroll
        for (int ks = 0; ks < 8; ++ks)
            A[ks] = __builtin_bit_cast(bfx8, *(const uint4*)&f2s[mt * 16 + lrow][ks * 32 + lk8]);
#pragma unroll
        for (int ct = 0; ct < 3; ++ct) {
            f32x4 acc = {0.f, 0.f, 0.f, 0.f};
#pragma unroll
            for (int ks = 0; ks < 8; ++ks) {
                bfx8 B = ld_frag_g(w2f + (size_t)(ct * 8 + ks) * 512 + lane * 8);
                acc = __builtin_amdgcn_mfma_f32_16x16x32_bf16(A[ks], B, acc, 0, 0, 0);
            }
            int col = ct * 16 + lrow;
            float bias = b2v[col];
#pragma unroll
            for (int r2 = 0; r2 < 4; ++r2) {
                int prow = mt * 16 + drow + r2;
                int p = base + prow;
                if (p < NPTS) {
                    size_t o = (size_t)NPTS * 8 + (size_t)p * 48 + col;
                    out[o] = shs_emb[(size_t)p * 48 + col] + acc[r2] + bias;
                }
            }
        }
    }
}

extern "C" void kernel_launch(void* const* d_in, const int* in_sizes, int n_in,
                              void* d_out, int out_size, void* d_ws, size_t ws_size,
                              hipStream_t stream) {
    const float* rays  = (const float*)d_in[0];
    const float* rot   = (const float*)d_in[1];
    const float* shs   = (const float*)d_in[3];
    const float* tme   = (const float*)d_in[5];
    const float* h_e   = (const float*)d_in[6];
    const float* sp    = (const float*)d_in[7];
    const float* tp    = (const float*)d_in[8];
    const float* wenc  = (const float*)d_in[9];
    const float* benc  = (const float*)d_in[10];
    const float* w1    = (const float*)d_in[11];
    const float* b1v   = (const float*)d_in[12];
    const float* w2    = (const float*)d_in[13];
    const float* b2v   = (const float*)d_in[14];
    float* out = (float*)d_out;
    unsigned short* wf = (unsigned short*)d_ws;  // 168 KB: wenc[8192] w1[65536] w2[12288] bf16 frags

    prep_w<<<(8192 + 255) / 256, 256, 0, stream>>>(wenc, wf, 32, 256, 8192);
    prep_w<<<65536 / 256, 256, 0, stream>>>(w1, wf + 8192, 256, 256, 65536);
    prep_w<<<12288 / 256, 256, 0, stream>>>(w2, wf + 73728, 256, 48, 12288);
    pass_copy<<<2048, 256, 0, stream>>>(rays, rot, h_e, out);
    fused_kernel<<<(NPTS + TM - 1) / TM, 256, 0, stream>>>(
        rays, tme, shs, sp, tp, wf, benc, b1v, b2v, out);
}

// Round 2
// 239.144 us; speedup vs baseline: 1.4178x; 1.4178x over previous
//
#include <hip/hip_runtime.h>
#include <hip/hip_fp16.h>

#define NPTS 500000
#define RPLANE 128
#define FDIM 32
#define PLSZ (RPLANE * RPLANE * FDIM)

typedef __bf16 bfx8 __attribute__((ext_vector_type(8)));
typedef float f32x4 __attribute__((ext_vector_type(4)));

__device__ __forceinline__ unsigned short f2bf(float f) {
    unsigned int u = __builtin_bit_cast(unsigned int, f);
    unsigned int r = (u + 0x7FFFu + ((u >> 16) & 1u)) >> 16;
    return (unsigned short)r;
}

__device__ __forceinline__ bfx8 ld_frag_g(const unsigned short* p) {
    uint4 raw = *(const uint4*)p;
    return __builtin_bit_cast(bfx8, raw);
}

struct h4v { __half2 a, b; };  // 4 fp16, 8 bytes

// Bilinear sample of 4 consecutive features from fp16 plane at (u->x, v->y).
__device__ __forceinline__ float4 interp4h(const __half* __restrict__ plane,
                                           float u, float v, int f0) {
    float x = fminf(fmaxf(u, 0.f), 1.f) * 127.0f;
    float y = fminf(fmaxf(v, 0.f), 1.f) * 127.0f;
    float xf = fminf(fmaxf(floorf(x), 0.f), 126.f);
    float yf = fminf(fmaxf(floorf(y), 0.f), 126.f);
    int x0 = (int)xf, y0 = (int)yf;
    float fx = x - xf, fy = y - yf;
    const __half* p = plane + (size_t)(y0 * RPLANE + x0) * FDIM + f0;
    h4v c00 = *(const h4v*)p;
    h4v c01 = *(const h4v*)(p + FDIM);
    h4v c10 = *(const h4v*)(p + RPLANE * FDIM);
    h4v c11 = *(const h4v*)(p + RPLANE * FDIM + FDIM);
    float2 a00l = __half22float2(c00.a), a00h = __half22float2(c00.b);
    float2 a01l = __half22float2(c01.a), a01h = __half22float2(c01.b);
    float2 a10l = __half22float2(c10.a), a10h = __half22float2(c10.b);
    float2 a11l = __half22float2(c11.a), a11h = __half22float2(c11.b);
    float w00 = (1.f - fx) * (1.f - fy);
    float w01 = fx * (1.f - fy);
    float w10 = (1.f - fx) * fy;
    float w11 = fx * fy;
    float4 r;
    r.x = a00l.x * w00 + a01l.x * w01 + a10l.x * w10 + a11l.x * w11;
    r.y = a00l.y * w00 + a01l.y * w01 + a10l.y * w10 + a11l.y * w11;
    r.z = a00h.x * w00 + a01h.x * w01 + a10h.x * w10 + a11h.x * w11;
    r.w = a00h.y * w00 + a01h.y * w01 + a10h.y * w10 + a11h.y * w11;
    return r;
}

// One prep kernel: repack all 3 weight mats to bf16 MFMA-B frags + convert planes to fp16.
// Frag layout: block b = ct*(K/32)+ks holds lane l elems j: B[ks*32+(l>>4)*8+j][ct*16+(l&15)].
__global__ void prep_all(const float* __restrict__ wenc, const float* __restrict__ w1,
                         const float* __restrict__ w2, const float* __restrict__ spf,
                         const float* __restrict__ tpf,
                         unsigned short* __restrict__ wf, __half* __restrict__ ph) {
    const int WTOT = 86016;
    const int PTOT = 6 * PLSZ;
    const int total = WTOT + PTOT;
    for (int i = blockIdx.x * blockDim.x + threadIdx.x; i < total;
         i += gridDim.x * blockDim.x) {
        if (i < WTOT) {
            const float* W;
            unsigned short* dst;
            int K, Ncols, idx;
            if (i < 8192)       { W = wenc; K = 32;  Ncols = 256; idx = i;         dst = wf; }
            else if (i < 73728) { W = w1;   K = 256; Ncols = 256; idx = i - 8192;  dst = wf + 8192; }
            else                { W = w2;   K = 256; Ncols = 48;  idx = i - 73728; dst = wf + 73728; }
            int j = idx & 7;
            int l = (idx >> 3) & 63;
            int b = idx >> 9;
            int KS = K >> 5;
            int ct = b / KS;
            int ks = b - ct * KS;
            int k = ks * 32 + ((l >> 4) << 3) + j;
            int col = ct * 16 + (l & 15);
            dst[idx] = f2bf(W[(size_t)k * Ncols + col]);
        } else {
            int j = i - WTOT;
            float v = (j < 3 * PLSZ) ? spf[j] : tpf[j - 3 * PLSZ];
            ph[j] = __float2half(v);
        }
    }
}

// Passthrough outputs: out[0:3N)=rays, out[3N:7N)=rot, out[7N:8N)=h_emb[:,0]
__global__ void pass_copy(const float* __restrict__ rays, const float* __restrict__ rot,
                          const float* __restrict__ h, float* __restrict__ out) {
    const int total = NPTS * 8;
    for (int i = blockIdx.x * blockDim.x + threadIdx.x; i < total; i += gridDim.x * blockDim.x) {
        float v;
        if (i < NPTS * 3) v = rays[i];
        else if (i < NPTS * 7) v = rot[i - NPTS * 3];
        else v = h[(i - NPTS * 7) * 2];
        out[i] = v;
    }
}

// Wave-synchronous fused kernel: each wave owns 32 points, no __syncthreads.
__global__ __launch_bounds__(256, 2) void fused2(
    const float* __restrict__ rays, const float* __restrict__ tme,
    const float* __restrict__ shs,
    const __half* __restrict__ sp, const __half* __restrict__ tp,
    const unsigned short* __restrict__ wf,
    const float* __restrict__ benc, const float* __restrict__ b1v,
    const float* __restrict__ b2v, float* __restrict__ out) {
    __shared__ unsigned short feat[4][32][40];    // per-wave [point][32feat+pad]
    __shared__ unsigned short hbuf[4][32][264];   // per-wave [point][256+pad], reused h1->h2
    const int tid = threadIdx.x;
    const int wid = tid >> 6;
    const int lane = tid & 63;
    const int p0 = blockIdx.x * 128 + wid * 32;
    if (p0 >= NPTS) return;
    unsigned short(*fw)[40] = feat[wid];
    unsigned short(*hw)[264] = hbuf[wid];

    // ---- gather: 8 lanes/point, 4 features/lane-task ----
#pragma unroll
    for (int it = 0; it < 4; ++it) {
        int task = it * 64 + lane;
        int pl = task >> 3;
        int fg = task & 7;
        int p = p0 + pl;
        float4 g = make_float4(0.f, 0.f, 0.f, 0.f);
        if (p < NPTS) {
            float px = rays[p * 3 + 0], py = rays[p * 3 + 1], pz = rays[p * 3 + 2];
            const float inv = 0.625f;
            float xn = fminf(fmaxf(px * inv, -1.f), 1.f) * 0.5f + 0.5f;
            float yn = fminf(fmaxf(py * inv, -1.f), 1.f) * 0.5f + 0.5f;
            float zn = fminf(fmaxf(pz * inv, -1.f), 1.f) * 0.5f + 0.5f;
            float t = fminf(fmaxf(tme[p], 0.f), 1.f);
            int f0 = fg << 2;
            float4 s0 = interp4h(sp, xn, yn, f0);
            float4 s1 = interp4h(sp + PLSZ, xn, zn, f0);
            float4 s2 = interp4h(sp + 2 * PLSZ, yn, zn, f0);
            float4 t0 = interp4h(tp, xn, t, f0);
            float4 t1 = interp4h(tp + PLSZ, yn, t, f0);
            float4 t2 = interp4h(tp + 2 * PLSZ, zn, t, f0);
            g.x = s0.x * s1.x * s2.x * t0.x * t1.x * t2.x;
            g.y = s0.y * s1.y * s2.y * t0.y * t1.y * t2.y;
            g.z = s0.z * s1.z * s2.z * t0.z * t1.z * t2.z;
            g.w = s0.w * s1.w * s2.w * t0.w * t1.w * t2.w;
        }
        ushort4 gb;
        gb.x = f2bf(g.x); gb.y = f2bf(g.y); gb.z = f2bf(g.z); gb.w = f2bf(g.w);
        *(ushort4*)&fw[pl][fg << 2] = gb;
    }

    const int lrow = lane & 15;
    const int lk8 = (lane >> 4) << 3;
    const int drow = (lane >> 4) << 2;

    // ---- layer 1: [32,32] @ [32,256] + b_enc, relu -> hw ----
    bfx8 a0 = __builtin_bit_cast(bfx8, *(const uint4*)&fw[lrow][lk8]);
    bfx8 a1 = __builtin_bit_cast(bfx8, *(const uint4*)&fw[16 + lrow][lk8]);
#pragma unroll
    for (int ct = 0; ct < 16; ++ct) {
        bfx8 b = ld_frag_g(wf + (size_t)ct * 512 + lane * 8);
        f32x4 z = {0.f, 0.f, 0.f, 0.f};
        f32x4 d0 = __builtin_amdgcn_mfma_f32_16x16x32_bf16(a0, b, z, 0, 0, 0);
        f32x4 d1 = __builtin_amdgcn_mfma_f32_16x16x32_bf16(a1, b, z, 0, 0, 0);
        float bias = benc[ct * 16 + lrow];
#pragma unroll
        for (int r = 0; r < 4; ++r) {
            hw[drow + r][ct * 16 + lrow] = f2bf(fmaxf(d0[r] + bias, 0.f));
            hw[16 + drow + r][ct * 16 + lrow] = f2bf(fmaxf(d1[r] + bias, 0.f));
        }
    }

    // ---- layer 2: [32,256] @ [256,256] + b1, relu -> hw (in place; A pre-read) ----
    const unsigned short* w1f = wf + 8192;
    bfx8 A0[8], A1[8];
#pragma unroll
    for (int ks = 0; ks < 8; ++ks) {
        A0[ks] = __builtin_bit_cast(bfx8, *(const uint4*)&hw[lrow][ks * 32 + lk8]);
        A1[ks] = __builtin_bit_cast(bfx8, *(const uint4*)&hw[16 + lrow][ks * 32 + lk8]);
    }
#pragma unroll
    for (int ct = 0; ct < 16; ++ct) {
        f32x4 acc0 = {0.f, 0.f, 0.f, 0.f};
        f32x4 acc1 = {0.f, 0.f, 0.f, 0.f};
#pragma unroll
        for (int ks = 0; ks < 8; ++ks) {
            bfx8 B = ld_frag_g(w1f + (size_t)(ct * 8 + ks) * 512 + lane * 8);
            acc0 = __builtin_amdgcn_mfma_f32_16x16x32_bf16(A0[ks], B, acc0, 0, 0, 0);
            acc1 = __builtin_amdgcn_mfma_f32_16x16x32_bf16(A1[ks], B, acc1, 0, 0, 0);
        }
        float bias = b1v[ct * 16 + lrow];
#pragma unroll
        for (int r = 0; r < 4; ++r) {
            hw[drow + r][ct * 16 + lrow] = f2bf(fmaxf(acc0[r] + bias, 0.f));
            hw[16 + drow + r][ct * 16 + lrow] = f2bf(fmaxf(acc1[r] + bias, 0.f));
        }
    }

    // ---- layer 3: [32,256] @ [256,48] + b2 + shs -> out ----
    const unsigned short* w2f = wf + 73728;
    bfx8 C0[8], C1[8];
#pragma unroll
    for (int ks = 0; ks < 8; ++ks) {
        C0[ks] = __builtin_bit_cast(bfx8, *(const uint4*)&hw[lrow][ks * 32 + lk8]);
        C1[ks] = __builtin_bit_cast(bfx8, *(const uint4*)&hw[16 + lrow][ks * 32 + lk8]);
    }
#pragma unroll
    for (int ct = 0; ct < 3; ++ct) {
        f32x4 acc0 = {0.f, 0.f, 0.f, 0.f};
        f32x4 acc1 = {0.f, 0.f, 0.f, 0.f};
#pragma unroll
        for (int ks = 0; ks < 8; ++ks) {
            bfx8 B = ld_frag_g(w2f + (size_t)(ct * 8 + ks) * 512 + lane * 8);
            acc0 = __builtin_amdgcn_mfma_f32_16x16x32_bf16(C0[ks], B, acc0, 0, 0, 0);
            acc1 = __builtin_amdgcn_mfma_f32_16x16x32_bf16(C1[ks], B, acc1, 0, 0, 0);
        }
        int col = ct * 16 + lrow;
        float bias = b2v[col];
#pragma unroll
        for (int r = 0; r < 4; ++r) {
            int pr = p0 + drow + r;
            if (pr < NPTS)
                out[(size_t)NPTS * 8 + (size_t)pr * 48 + col] =
                    shs[(size_t)pr * 48 + col] + acc0[r] + bias;
            int pr2 = p0 + 16 + drow + r;
            if (pr2 < NPTS)
                out[(size_t)NPTS * 8 + (size_t)pr2 * 48 + col] =
                    shs[(size_t)pr2 * 48 + col] + acc1[r] + bias;
        }
    }
}

extern "C" void kernel_launch(void* const* d_in, const int* in_sizes, int n_in,
                              void* d_out, int out_size, void* d_ws, size_t ws_size,
                              hipStream_t stream) {
    const float* rays = (const float*)d_in[0];
    const float* rot  = (const float*)d_in[1];
    const float* shs  = (const float*)d_in[3];
    const float* tme  = (const float*)d_in[5];
    const float* h_e  = (const float*)d_in[6];
    const float* spf  = (const float*)d_in[7];
    const float* tpf  = (const float*)d_in[8];
    const float* wenc = (const float*)d_in[9];
    const float* benc = (const float*)d_in[10];
    const float* w1   = (const float*)d_in[11];
    const float* b1v  = (const float*)d_in[12];
    const float* w2   = (const float*)d_in[13];
    const float* b2v  = (const float*)d_in[14];
    float* out = (float*)d_out;
    unsigned short* wf = (unsigned short*)d_ws;    // 86016 shorts of weight frags
    __half* ph = (__half*)(wf + 86016);            // 6*PLSZ fp16 plane cache (~6.3 MB)

    prep_all<<<3408, 256, 0, stream>>>(wenc, w1, w2, spf, tpf, wf, ph);
    pass_copy<<<2048, 256, 0, stream>>>(rays, rot, h_e, out);
    fused2<<<(NPTS + 127) / 128, 256, 0, stream>>>(
        rays, tme, shs, ph, ph + 3 * PLSZ, wf, benc, b1v, b2v, out);
}